// Round 2
// baseline (3564.727 us; speedup 1.0000x reference)
//
#include <hip/hip_runtime.h>
#include <hip/hip_bf16.h>
#include <cstdint>

// ---------------------------------------------------------------------------
// BiLSTM layer, persistent-kernel design (round 2: device-scope h exchange).
//   B=64, S=512, I=H=1024.  out = [fwd(B,S,H) | bwd(B,S,H)] fp32.
// 256 blocks x 512 threads (8 waves), 1 block/CU (160 KiB LDS forces it).
//   dir = bid&1, db = bid>>1 : block owns hidden units n0 = db*8 .. n0+7.
// Weights (W_ih|W_hh, K=2048) live permanently in VGPRs as MFMA B-fragments.
// Cross-block h exchange: stores are agent-scope atomics (sc0|sc1 -> MALL),
// loads are global_load_lds with aux=SC0|SC1=17 (bypass L1/L2). No fences,
// no cache flushes in the hot loop — coherence point is the Infinity Cache.
// ---------------------------------------------------------------------------

typedef __bf16 bf16_t;
typedef bf16_t bf16x8 __attribute__((ext_vector_type(8)));
typedef float  f32x4  __attribute__((ext_vector_type(4)));

#define DEVI __device__ __forceinline__

constexpr int Bb = 64, Ss = 512, Ii = 1024, Hh = 1024;
constexpr int NBLK_DIR = 128;
constexpr size_t WS_CNT    = 0;            // 1024 ints (2 dirs x 512 steps)
constexpr size_t WS_HRING  = 4096;         // 2*2*64*1024 bf16 = 524288 B
constexpr size_t WS_XBF    = 1ull << 20;   // x in bf16, t-major [dir][t][b][i]
constexpr size_t XBF_BYTES = 2ull * Ss * Bb * Ii * 2;   // 128 MiB
constexpr size_t WS_NEED_XBF = WS_XBF + XBF_BYTES;
constexpr int LDS_TOTAL = 163840;          // PA 64K | PB 64K | part 32K

DEVI float fast_sig(float x) {
  float z = __expf(-fabsf(x));
  float r = __builtin_amdgcn_rcpf(1.f + z);
  return x >= 0.f ? r : z * r;
}
DEVI float fast_tanh(float x) {
  float z = __expf(-2.f * fabsf(x));
  float r = (1.f - z) * __builtin_amdgcn_rcpf(1.f + z);
  return x >= 0.f ? r : -r;
}
DEVI bf16x8 cvt8(f32x4 a, f32x4 b) {
  bf16x8 r;
  r[0] = (bf16_t)a[0]; r[1] = (bf16_t)a[1]; r[2] = (bf16_t)a[2]; r[3] = (bf16_t)a[3];
  r[4] = (bf16_t)b[0]; r[5] = (bf16_t)b[1]; r[6] = (bf16_t)b[2]; r[7] = (bf16_t)b[3];
  return r;
}
DEVI f32x4 mfma16(bf16x8 a, bf16x8 b, f32x4 c) {
  return __builtin_amdgcn_mfma_f32_16x16x32_bf16(a, b, c, 0, 0, 0);
}

// aux: CPol bits, SC0=1, NT=2, SC1=16.  17 = SC0|SC1 = device-coherent (MALL).
#define GLDS16(g, s)                                                           \
  __builtin_amdgcn_global_load_lds(                                            \
      (const __attribute__((address_space(1))) void*)(const void*)(g),         \
      (__attribute__((address_space(3))) void*)(void*)(s), 16, 0, 0)
#define GLDS16_COH(g, s)                                                       \
  __builtin_amdgcn_global_load_lds(                                            \
      (const __attribute__((address_space(1))) void*)(const void*)(g),         \
      (__attribute__((address_space(3))) void*)(void*)(s), 16, 0, 17)
#define WAIT_LGKM0 asm volatile("s_waitcnt lgkmcnt(0)" ::: "memory")
#define WAIT_VM(n) asm volatile("s_waitcnt vmcnt(" #n ")" ::: "memory")
#define BARRIER_RAW                                                            \
  do { __builtin_amdgcn_s_barrier(); __builtin_amdgcn_sched_barrier(0); } while (0)

__global__ void k_init(int* cnt) {
  int i = threadIdx.x;
  if (i < 1024) cnt[i] = 0;
}

// x fp32 [dir][b][t][i]  ->  bf16 t-major [dir][t][b][i]
__global__ void k_convx(const float* __restrict__ xf, const float* __restrict__ xb,
                        bf16_t* __restrict__ dst) {
  size_t og = (size_t)blockIdx.x * blockDim.x + threadIdx.x;  // 8,388,608 granules
  int i8  = (int)(og & 127);
  int b   = (int)((og >> 7) & 63);
  int t   = (int)((og >> 13) & 511);
  int dir = (int)(og >> 22);
  const float* src = (dir ? xb : xf) + (((size_t)b * Ss + t) * Ii + (size_t)i8 * 8);
  f32x4 a = *(const f32x4*)src;
  f32x4 c = *(const f32x4*)(src + 4);
  *(bf16x8*)(dst + og * 8) = cvt8(a, c);
}

template <bool XBF>
__global__ void __launch_bounds__(512, 2)
k_lstm(const float* __restrict__ xf, const float* __restrict__ xb,
       const float* __restrict__ Wih_f, const float* __restrict__ Whh_f,
       const float* __restrict__ bih_f, const float* __restrict__ bhh_f,
       const float* __restrict__ Wih_b, const float* __restrict__ Whh_b,
       const float* __restrict__ bih_b, const float* __restrict__ bhh_b,
       float* __restrict__ out,
       const bf16_t* __restrict__ xbfin, bf16_t* __restrict__ hring,
       int* __restrict__ cnt) {
  extern __shared__ char lds[];
  char* PA = lds;                 // half-panel [64 rows][512 k] bf16 = 64 KiB
  char* PB = lds + 65536;
  float* part = (float*)(lds + 131072);   // [4 kq][64 b][32 c] f32 = 32 KiB

  const int tid = threadIdx.x;
  const int bid = blockIdx.x;
  const int dir = bid & 1;
  const int db  = bid >> 1;
  const int n0  = db * 8;
  const int w   = tid >> 6, l = tid & 63;
  const int u   = l >> 4, l15 = l & 15;
  const int m   = w & 1;        // M swath (rows 32m..32m+31)
  const int kq  = w >> 1;       // K stripe (128-elem blocks kq of each half-panel)

  const float* Wih = dir ? Wih_b : Wih_f;
  const float* Whh = dir ? Whh_b : Whh_f;
  const float* bih = dir ? bih_b : bih_f;
  const float* bhh = dir ? bhh_b : bhh_f;
  const float* x32 = dir ? xb : xf;
  const bf16_t* xbase = xbfin + (size_t)dir * Ss * Bb * Ii;       // [t][b][i]
  bf16_t* hr = hring + (size_t)dir * 2 * Bb * Hh;                 // [par][b][h]
  float* outD = out + (size_t)dir * Bb * Ss * Hh;
  int* mycnt = cnt + dir * 512;

  // ---- one-time: W into VGPRs as B-fragments -------------------------------
  bf16x8 wr[2][2][4][2];
#pragma unroll
  for (int mat = 0; mat < 2; ++mat)
#pragma unroll
    for (int p = 0; p < 2; ++p)
#pragma unroll
      for (int ks = 0; ks < 4; ++ks)
#pragma unroll
        for (int nt = 0; nt < 2; ++nt) {
          int c = nt * 16 + l15;
          int j = (c >> 3) * 1024 + n0 + (c & 7);
          int k = p * 512 + kq * 128 + ks * 32 + u * 8;
          const float* sp = (mat ? Whh : Wih) + (size_t)j * 1024 + k;
          wr[mat][p][ks][nt] = cvt8(*(const f32x4*)sp, *(const f32x4*)(sp + 4));
        }

  // bias for the elementwise phase: thread -> (eb = tid>>3, en = tid&7)
  const int eb = tid >> 3, en = tid & 7;
  const int nj = n0 + en;
  float bi0 = bih[nj] + bhh[nj];
  float bi1 = bih[1024 + nj] + bhh[1024 + nj];
  float bi2 = bih[2048 + nj] + bhh[2048 + nj];
  float bi3 = bih[3072 + nj] + bhh[3072 + nj];

  // A-fragment LDS offsets (panel [64][512]bf16, granule swizzle slot^(row&7))
  int aoff0[4], aoff1[4];
#pragma unroll
  for (int ks = 0; ks < 4; ++ks) {
    int r0 = m * 32 + l15;
    int r1 = r0 + 16;
    int sl = kq * 16 + ks * 4 + u;
    aoff0[ks] = r0 * 1024 + ((sl ^ (r0 & 7)) << 4);
    aoff1[ks] = r1 * 1024 + ((sl ^ (r1 & 7)) << 4);
  }

  // stage DMA: wave w writes rows w*8+i; lane l writes LDS granule (r,l),
  // reads source granule (r, l^i) [i=r&7] -> matches read-side XOR.
  auto STAGE_DMA = [&](char* panel, const bf16_t* srcb) {
#pragma unroll
    for (int i = 0; i < 8; ++i) {
      const bf16_t* gp = srcb + (size_t)(w * 8 + i) * 1024 + ((l ^ i) << 3);
      char* sp = panel + (w * 8 + i) * 1024;
      GLDS16(gp, sp);
    }
  };
  // h panels: device-coherent DMA (bypass L1/L2; data lives at MALL)
  auto STAGE_H = [&](char* panel, const bf16_t* srcb) {
#pragma unroll
    for (int i = 0; i < 8; ++i) {
      const bf16_t* gp = srcb + (size_t)(w * 8 + i) * 1024 + ((l ^ i) << 3);
      char* sp = panel + (w * 8 + i) * 1024;
      GLDS16_COH(gp, sp);
    }
  };
  // fallback: fp32 x staged through regs + cvt (same LDS layout)
  auto STAGE_XF = [&](char* panel, const float* srcb) {
#pragma unroll
    for (int i = 0; i < 8; ++i) {
      int r = w * 8 + i;
      const float* sp = srcb + (size_t)r * (Ss * Ii) + ((l ^ i) << 3);
      f32x4 a = *(const f32x4*)sp;
      f32x4 b = *(const f32x4*)(sp + 4);
      *(bf16x8*)(panel + r * 1024 + l * 16) = cvt8(a, b);
    }
  };

  f32x4 acc00, acc01, acc10, acc11;
#define COMPUTE(panel, matC, pC)                                               \
  do {                                                                         \
    _Pragma("unroll") for (int ks = 0; ks < 4; ++ks) {                         \
      bf16x8 a0_ = *(const bf16x8*)((panel) + aoff0[ks]);                      \
      bf16x8 a1_ = *(const bf16x8*)((panel) + aoff1[ks]);                      \
      acc00 = mfma16(a0_, wr[matC][pC][ks][0], acc00);                         \
      acc01 = mfma16(a0_, wr[matC][pC][ks][1], acc01);                         \
      acc10 = mfma16(a1_, wr[matC][pC][ks][0], acc10);                         \
      acc11 = mfma16(a1_, wr[matC][pC][ks][1], acc11);                         \
    }                                                                          \
  } while (0)

  float c_reg = 0.f;

  // prologue: stage X half-panel 0 of first timestep into PA
  {
    int t0 = dir ? (Ss - 1) : 0;
    if constexpr (XBF) STAGE_DMA(PA, xbase + (size_t)t0 * (Bb * Ii));
    else               STAGE_XF(PA, x32 + (size_t)t0 * Ii);
    WAIT_VM(0); WAIT_LGKM0; BARRIER_RAW;
  }

  for (int step = 0; step < Ss; ++step) {
    const int t  = dir ? (Ss - 1 - step) : step;
    const int tn = dir ? (Ss - 2 - step) : (step + 1);
    const bf16_t* hbase = hr + (size_t)((step - 1) & 1) * (Bb * Hh);

    acc00 = f32x4{0.f, 0.f, 0.f, 0.f}; acc01 = acc00; acc10 = acc00; acc11 = acc00;

    // A1: issue X1 -> PB
    if constexpr (XBF) STAGE_DMA(PB, xbase + (size_t)t * (Bb * Ii) + 512);
    else               STAGE_XF(PB, x32 + (size_t)t * Ii + 512);
    // A3: compute X0 from PA
    COMPUTE(PA, 0, 0);
    // A4: drain LDS reads, poll h_{t-1} ready, barrier
    WAIT_LGKM0;
    if (step > 0 && tid == 0) {
      while (__hip_atomic_load(&mycnt[step - 1], __ATOMIC_RELAXED,
                               __HIP_MEMORY_SCOPE_AGENT) < NBLK_DIR)
        __builtin_amdgcn_s_sleep(1);
    }
    BARRIER_RAW;
    // A5/A6: issue H0 -> PA; ensure X1 landed
    if (step > 0) {
      STAGE_H(PA, hbase);
      WAIT_VM(8);
      BARRIER_RAW;
    } else {
      WAIT_VM(0); BARRIER_RAW;
    }
    // A7: compute X1
    COMPUTE(PB, 0, 1);
    WAIT_LGKM0; BARRIER_RAW;                       // A8
    if (step > 0) {
      STAGE_H(PB, hbase + 512);                    // A9: issue H1 -> PB
      WAIT_VM(8); BARRIER_RAW;                     // A10: H0 landed
      COMPUTE(PA, 1, 0);                           // A11: compute H0
      WAIT_LGKM0; BARRIER_RAW;                     // A12
    }
    // A13: prefetch next step's X0 -> PA
    if (step < Ss - 1) {
      if constexpr (XBF) STAGE_DMA(PA, xbase + (size_t)tn * (Bb * Ii));
      else               STAGE_XF(PA, x32 + (size_t)tn * Ii);
    }
    if (step > 0) {
      if (step < Ss - 1) { WAIT_VM(8); } else { WAIT_VM(0); }  // A14: H1 landed
      BARRIER_RAW;
      COMPUTE(PB, 1, 1);                           // A16: compute H1
    }
    WAIT_LGKM0; BARRIER_RAW;                       // A17

    // A18: write K-partials to LDS  part[kq][row][col]
#pragma unroll
    for (int rr = 0; rr < 2; ++rr)
#pragma unroll
      for (int nt = 0; nt < 2; ++nt) {
        f32x4 a = (rr == 0) ? (nt == 0 ? acc00 : acc01) : (nt == 0 ? acc10 : acc11);
#pragma unroll
        for (int q = 0; q < 4; ++q) {
          int R = m * 32 + rr * 16 + u * 4 + q;
          int C = nt * 16 + l15;
          part[(kq * 64 + R) * 32 + C] = a[q];
        }
      }
    WAIT_LGKM0; BARRIER_RAW;

    // A19: elementwise gates; thread -> (eb, en)
    {
      float g0 = bi0, g1 = bi1, g2 = bi2, g3 = bi3;
#pragma unroll
      for (int q = 0; q < 4; ++q) {
        const float* pp = &part[(q * 64 + eb) * 32];
        g0 += pp[en]; g1 += pp[8 + en]; g2 += pp[16 + en]; g3 += pp[24 + en];
      }
      float ig = fast_sig(g0), fg = fast_sig(g1);
      float gg = fast_tanh(g2), og = fast_sig(g3);
      c_reg = fg * c_reg + ig * gg;
      float h = og * fast_tanh(c_reg);
      outD[(size_t)eb * (Ss * Hh) + (size_t)t * Hh + n0 + en] = h;
      // agent-scope packed store of (en, en+1) -> visible at MALL, never dirty L2
      float hn = __shfl_xor(h, 1);
      if (!(tid & 1)) {
        union { bf16_t b[2]; uint32_t u32; } pk;
        pk.b[0] = (bf16_t)h; pk.b[1] = (bf16_t)hn;
        uint32_t* dst = (uint32_t*)&hr[(size_t)(step & 1) * (Bb * Hh) +
                                       (size_t)eb * Hh + n0 + en];
        __hip_atomic_store(dst, pk.u32, __ATOMIC_RELAXED, __HIP_MEMORY_SCOPE_AGENT);
      }
    }
    // A20: drain stores (sc1 stores complete at MALL when vmcnt retires),
    // then arrive. No fence needed: nothing cross-block is L2-dirty.
    WAIT_VM(0); WAIT_LGKM0; BARRIER_RAW;
    if (tid == 0) {
      __hip_atomic_fetch_add(&mycnt[step], 1, __ATOMIC_RELAXED,
                             __HIP_MEMORY_SCOPE_AGENT);
    }
  }
#undef COMPUTE
}

extern "C" void kernel_launch(void* const* d_in, const int* in_sizes, int n_in,
                              void* d_out, int out_size, void* d_ws, size_t ws_size,
                              hipStream_t stream) {
  (void)in_sizes; (void)n_in; (void)out_size;
  const float* xf    = (const float*)d_in[0];
  const float* xb    = (const float*)d_in[1];
  const float* Wih_f = (const float*)d_in[2];
  const float* Whh_f = (const float*)d_in[3];
  const float* bih_f = (const float*)d_in[4];
  const float* bhh_f = (const float*)d_in[5];
  const float* Wih_b = (const float*)d_in[6];
  const float* Whh_b = (const float*)d_in[7];
  const float* bih_b = (const float*)d_in[8];
  const float* bhh_b = (const float*)d_in[9];
  float* outp = (float*)d_out;
  char* ws = (char*)d_ws;
  int* cntp = (int*)(ws + WS_CNT);
  bf16_t* hringp = (bf16_t*)(ws + WS_HRING);
  const bf16_t* xbfp = (const bf16_t*)(ws + WS_XBF);
  const bool use_xbf = ws_size >= WS_NEED_XBF;

  hipLaunchKernelGGL(k_init, dim3(1), dim3(1024), 0, stream, cntp);
  if (use_xbf) {
    hipLaunchKernelGGL(k_convx, dim3(32768), dim3(256), 0, stream,
                       xf, xb, (bf16_t*)(ws + WS_XBF));
  }

  void* args[] = {&xf, &xb, &Wih_f, &Whh_f, &bih_f, &bhh_f,
                  &Wih_b, &Whh_b, &bih_b, &bhh_b,
                  &outp, &xbfp, &hringp, &cntp};
  if (use_xbf) {
    void (*kp)(const float*, const float*, const float*, const float*,
               const float*, const float*, const float*, const float*,
               const float*, const float*, float*, const bf16_t*, bf16_t*, int*) =
        k_lstm<true>;
    hipFuncSetAttribute((const void*)kp, hipFuncAttributeMaxDynamicSharedMemorySize,
                        LDS_TOTAL);
    hipLaunchCooperativeKernel((const void*)kp, dim3(256), dim3(512), args,
                               LDS_TOTAL, stream);
  } else {
    void (*kp)(const float*, const float*, const float*, const float*,
               const float*, const float*, const float*, const float*,
               const float*, const float*, float*, const bf16_t*, bf16_t*, int*) =
        k_lstm<false>;
    hipFuncSetAttribute((const void*)kp, hipFuncAttributeMaxDynamicSharedMemorySize,
                        LDS_TOTAL);
    hipLaunchCooperativeKernel((const void*)kp, dim3(256), dim3(512), args,
                               LDS_TOTAL, stream);
  }
}

// Round 3
// 3439.297 us; speedup vs baseline: 1.0365x; 1.0365x over previous
//
#include <hip/hip_runtime.h>
#include <hip/hip_bf16.h>
#include <cstdint>

// ---------------------------------------------------------------------------
// BiLSTM layer, persistent-kernel design (round 3).
//   B=64, S=512, I=H=1024.  out = [fwd(B,S,H) | bwd(B,S,H)] fp32.
// 256 blocks x 512 threads (8 waves), 1 block/CU.
//   dir = bid&1, db = bid>>1 : block owns hidden units n0 = db*8 .. n0+7.
// Weights (W_ih|W_hh, K=2048) live permanently in VGPRs as MFMA B-fragments.
// Cross-block h exchange: agent-scope packed stores (write-through to MALL),
// DMA loads with aux=SC0|SC1 (bypass L1/L2). Arrival: per-block FLAG array
// (no same-address atomic convoy); release drains only what it must.
// Round-3 deltas: flag-array sync, part-buffer XOR swizzle (bank conflicts),
// vmcnt re-choreography so the release never waits on the x prefetch.
// ---------------------------------------------------------------------------

typedef __bf16 bf16_t;
typedef bf16_t bf16x8 __attribute__((ext_vector_type(8)));
typedef float  f32x4  __attribute__((ext_vector_type(4)));

#define DEVI __device__ __forceinline__

constexpr int Bb = 64, Ss = 512, Ii = 1024, Hh = 1024;
constexpr size_t WS_FLAGS  = 0;            // 256 ints (2 dirs x 128 blocks)
constexpr size_t WS_HRING  = 4096;         // 2*2*64*1024 bf16 = 524288 B
constexpr size_t WS_XBF    = 1ull << 20;   // x in bf16, t-major [dir][t][b][i]
constexpr size_t XBF_BYTES = 2ull * Ss * Bb * Ii * 2;   // 128 MiB
constexpr size_t WS_NEED_XBF = WS_XBF + XBF_BYTES;
constexpr int LDS_TOTAL = 163840;          // PA 64K | PB 64K | part 32K

DEVI float fast_sig(float x) {
  float z = __expf(-fabsf(x));
  float r = __builtin_amdgcn_rcpf(1.f + z);
  return x >= 0.f ? r : z * r;
}
DEVI float fast_tanh(float x) {
  float z = __expf(-2.f * fabsf(x));
  float r = (1.f - z) * __builtin_amdgcn_rcpf(1.f + z);
  return x >= 0.f ? r : -r;
}
DEVI bf16x8 cvt8(f32x4 a, f32x4 b) {
  bf16x8 r;
  r[0] = (bf16_t)a[0]; r[1] = (bf16_t)a[1]; r[2] = (bf16_t)a[2]; r[3] = (bf16_t)a[3];
  r[4] = (bf16_t)b[0]; r[5] = (bf16_t)b[1]; r[6] = (bf16_t)b[2]; r[7] = (bf16_t)b[3];
  return r;
}
DEVI f32x4 mfma16(bf16x8 a, bf16x8 b, f32x4 c) {
  return __builtin_amdgcn_mfma_f32_16x16x32_bf16(a, b, c, 0, 0, 0);
}

// aux: CPol bits, SC0=1, NT=2, SC1=16.  17 = SC0|SC1 = device-coherent (MALL).
#define GLDS16(g, s)                                                           \
  __builtin_amdgcn_global_load_lds(                                            \
      (const __attribute__((address_space(1))) void*)(const void*)(g),         \
      (__attribute__((address_space(3))) void*)(void*)(s), 16, 0, 0)
#define GLDS16_COH(g, s)                                                       \
  __builtin_amdgcn_global_load_lds(                                            \
      (const __attribute__((address_space(1))) void*)(const void*)(g),         \
      (__attribute__((address_space(3))) void*)(void*)(s), 16, 0, 17)
#define WAIT_LGKM0 asm volatile("s_waitcnt lgkmcnt(0)" ::: "memory")
#define WAIT_VM(n) asm volatile("s_waitcnt vmcnt(" #n ")" ::: "memory")
#define BARRIER_RAW                                                            \
  do { __builtin_amdgcn_s_barrier(); __builtin_amdgcn_sched_barrier(0); } while (0)

__global__ void k_init(int* flags) {
  int i = threadIdx.x;
  if (i < 256) flags[i] = 0;
}

// x fp32 [dir][b][t][i]  ->  bf16 t-major [dir][t][b][i]
__global__ void k_convx(const float* __restrict__ xf, const float* __restrict__ xb,
                        bf16_t* __restrict__ dst) {
  size_t og = (size_t)blockIdx.x * blockDim.x + threadIdx.x;  // 8,388,608 granules
  int i8  = (int)(og & 127);
  int b   = (int)((og >> 7) & 63);
  int t   = (int)((og >> 13) & 511);
  int dir = (int)(og >> 22);
  const float* src = (dir ? xb : xf) + (((size_t)b * Ss + t) * Ii + (size_t)i8 * 8);
  f32x4 a = *(const f32x4*)src;
  f32x4 c = *(const f32x4*)(src + 4);
  *(bf16x8*)(dst + og * 8) = cvt8(a, c);
}

template <bool XBF>
__global__ void __launch_bounds__(512, 2)
k_lstm(const float* __restrict__ xf, const float* __restrict__ xb,
       const float* __restrict__ Wih_f, const float* __restrict__ Whh_f,
       const float* __restrict__ bih_f, const float* __restrict__ bhh_f,
       const float* __restrict__ Wih_b, const float* __restrict__ Whh_b,
       const float* __restrict__ bih_b, const float* __restrict__ bhh_b,
       float* __restrict__ out,
       const bf16_t* __restrict__ xbfin, bf16_t* __restrict__ hring,
       int* __restrict__ flags) {
  extern __shared__ char lds[];
  char* PA = lds;                 // half-panel [64 rows][512 k] bf16 = 64 KiB
  char* PB = lds + 65536;
  float* part = (float*)(lds + 131072);   // [4 kq][64 b][32 c] f32 = 32 KiB

  const int tid = threadIdx.x;
  const int bid = blockIdx.x;
  const int dir = bid & 1;
  const int db  = bid >> 1;
  const int n0  = db * 8;
  const int w   = tid >> 6, l = tid & 63;
  const int u   = l >> 4, l15 = l & 15;
  const int m   = w & 1;        // M swath (rows 32m..32m+31)
  const int kq  = w >> 1;       // K stripe (128-elem blocks of each half-panel)

  const float* Wih = dir ? Wih_b : Wih_f;
  const float* Whh = dir ? Whh_b : Whh_f;
  const float* bih = dir ? bih_b : bih_f;
  const float* bhh = dir ? bhh_b : bhh_f;
  const float* x32 = dir ? xb : xf;
  const bf16_t* xbase = xbfin + (size_t)dir * Ss * Bb * Ii;       // [t][b][i]
  bf16_t* hr = hring + (size_t)dir * 2 * Bb * Hh;                 // [par][b][h]
  float* outD = out + (size_t)dir * Bb * Ss * Hh;
  int* myflags = flags + dir * 128;

  // ---- one-time: W into VGPRs as B-fragments -------------------------------
  bf16x8 wr[2][2][4][2];
#pragma unroll
  for (int mat = 0; mat < 2; ++mat)
#pragma unroll
    for (int p = 0; p < 2; ++p)
#pragma unroll
      for (int ks = 0; ks < 4; ++ks)
#pragma unroll
        for (int nt = 0; nt < 2; ++nt) {
          int c = nt * 16 + l15;
          int j = (c >> 3) * 1024 + n0 + (c & 7);
          int k = p * 512 + kq * 128 + ks * 32 + u * 8;
          const float* sp = (mat ? Whh : Wih) + (size_t)j * 1024 + k;
          wr[mat][p][ks][nt] = cvt8(*(const f32x4*)sp, *(const f32x4*)(sp + 4));
        }

  // bias for the elementwise phase: thread -> (eb = tid>>3, en = tid&7)
  const int eb = tid >> 3, en = tid & 7;
  const int nj = n0 + en;
  float bi0 = bih[nj] + bhh[nj];
  float bi1 = bih[1024 + nj] + bhh[1024 + nj];
  float bi2 = bih[2048 + nj] + bhh[2048 + nj];
  float bi3 = bih[3072 + nj] + bhh[3072 + nj];

  // A-fragment LDS offsets (panel [64][512]bf16, granule swizzle slot^(row&7))
  int aoff0[4], aoff1[4];
#pragma unroll
  for (int ks = 0; ks < 4; ++ks) {
    int r0 = m * 32 + l15;
    int r1 = r0 + 16;
    int sl = kq * 16 + ks * 4 + u;
    aoff0[ks] = r0 * 1024 + ((sl ^ (r0 & 7)) << 4);
    aoff1[ks] = r1 * 1024 + ((sl ^ (r1 & 7)) << 4);
  }

  // stage DMA: wave w writes rows w*8+i; lane l writes LDS granule (r,l),
  // reads source granule (r, l^i) [i=r&7] -> matches read-side XOR.
  auto STAGE_DMA = [&](char* panel, const bf16_t* srcb) {
#pragma unroll
    for (int i = 0; i < 8; ++i) {
      const bf16_t* gp = srcb + (size_t)(w * 8 + i) * 1024 + ((l ^ i) << 3);
      char* sp = panel + (w * 8 + i) * 1024;
      GLDS16(gp, sp);
    }
  };
  // h panels: device-coherent DMA (bypass L1/L2; data lives at MALL)
  auto STAGE_H = [&](char* panel, const bf16_t* srcb) {
#pragma unroll
    for (int i = 0; i < 8; ++i) {
      const bf16_t* gp = srcb + (size_t)(w * 8 + i) * 1024 + ((l ^ i) << 3);
      char* sp = panel + (w * 8 + i) * 1024;
      GLDS16_COH(gp, sp);
    }
  };
  // fallback: fp32 x staged through regs + cvt (same LDS layout)
  auto STAGE_XF = [&](char* panel, const float* srcb) {
#pragma unroll
    for (int i = 0; i < 8; ++i) {
      int r = w * 8 + i;
      const float* sp = srcb + (size_t)r * (Ss * Ii) + ((l ^ i) << 3);
      f32x4 a = *(const f32x4*)sp;
      f32x4 b = *(const f32x4*)(sp + 4);
      *(bf16x8*)(panel + r * 1024 + l * 16) = cvt8(a, b);
    }
  };

  f32x4 acc00, acc01, acc10, acc11;
#define COMPUTE(panel, matC, pC)                                               \
  do {                                                                         \
    _Pragma("unroll") for (int ks = 0; ks < 4; ++ks) {                         \
      bf16x8 a0_ = *(const bf16x8*)((panel) + aoff0[ks]);                      \
      bf16x8 a1_ = *(const bf16x8*)((panel) + aoff1[ks]);                      \
      acc00 = mfma16(a0_, wr[matC][pC][ks][0], acc00);                         \
      acc01 = mfma16(a0_, wr[matC][pC][ks][1], acc01);                         \
      acc10 = mfma16(a1_, wr[matC][pC][ks][0], acc10);                         \
      acc11 = mfma16(a1_, wr[matC][pC][ks][1], acc11);                         \
    }                                                                          \
  } while (0)

  float c_reg = 0.f;

  // prologue: stage X half-panel 0 of first timestep into PA
  {
    int t0 = dir ? (Ss - 1) : 0;
    if constexpr (XBF) STAGE_DMA(PA, xbase + (size_t)t0 * (Bb * Ii));
    else               STAGE_XF(PA, x32 + (size_t)t0 * Ii);
    WAIT_VM(0); WAIT_LGKM0; BARRIER_RAW;
  }

  for (int step = 0; step < Ss; ++step) {
    const int t  = dir ? (Ss - 1 - step) : step;
    const int tn = dir ? (Ss - 2 - step) : (step + 1);
    const bf16_t* hbase = hr + (size_t)((step - 1) & 1) * (Bb * Hh);

    acc00 = f32x4{0.f, 0.f, 0.f, 0.f}; acc01 = acc00; acc10 = acc00; acc11 = acc00;

    // A1: issue X1 -> PB  [vm: X1(8)]
    if constexpr (XBF) STAGE_DMA(PB, xbase + (size_t)t * (Bb * Ii) + 512);
    else               STAGE_XF(PB, x32 + (size_t)t * Ii + 512);
    // A3: compute X0 from PA (ready via prev A20 drain+barrier / prologue)
    COMPUTE(PA, 0, 0);
    // A4: drain LDS reads; poll h_{t-1} flags (one flag per producer block)
    WAIT_LGKM0;
    if (step > 0 && tid < 128) {
      const int* fp = &myflags[tid];
      while (__hip_atomic_load(fp, __ATOMIC_RELAXED, __HIP_MEMORY_SCOPE_AGENT) < step) {
      }
    }
    BARRIER_RAW;
    // A5/A6: issue H0 -> PA; ensure X1 landed  [vm: X1(8)+H0(8) -> wait<=8]
    if (step > 0) {
      STAGE_H(PA, hbase);
      WAIT_VM(8);
      BARRIER_RAW;
    } else {
      WAIT_VM(0); BARRIER_RAW;
    }
    // A7: compute X1
    COMPUTE(PB, 0, 1);
    WAIT_LGKM0; BARRIER_RAW;                       // A8
    if (step > 0) {
      STAGE_H(PB, hbase + 512);                    // A9: H1 -> PB [H0(8)+H1(8)]
      WAIT_VM(8); BARRIER_RAW;                     // A10: H0 landed
      COMPUTE(PA, 1, 0);                           // A11: compute H0
      WAIT_LGKM0; BARRIER_RAW;                     // A12
    }
    // A13: prefetch next step's X0 -> PA (PA free: last read A11/A3+barriers)
    if (step < Ss - 1) {
      if constexpr (XBF) STAGE_DMA(PA, xbase + (size_t)tn * (Bb * Ii));
      else               STAGE_XF(PA, x32 + (size_t)tn * Ii);
    }
    if (step > 0) {
      // A14: drain H1 exactly, leave X0' in flight (in-order retirement:
      // H1 is older than X0')
      if (step < Ss - 1) { WAIT_VM(8); } else { WAIT_VM(0); }
      BARRIER_RAW;
      COMPUTE(PB, 1, 1);                           // A16: compute H1
    }
    WAIT_LGKM0; BARRIER_RAW;                       // A17

    // A18: write K-partials to LDS, XOR-swizzled column: Cs = C ^ ((R&7)<<2)
    // -> write side 2 lanes/bank, read side 2 lanes/bank (free, m136)
#pragma unroll
    for (int rr = 0; rr < 2; ++rr)
#pragma unroll
      for (int nt = 0; nt < 2; ++nt) {
        f32x4 a = (rr == 0) ? (nt == 0 ? acc00 : acc01) : (nt == 0 ? acc10 : acc11);
#pragma unroll
        for (int q = 0; q < 4; ++q) {
          int R = m * 32 + rr * 16 + u * 4 + q;
          int C = nt * 16 + l15;
          part[(kq * 64 + R) * 32 + (C ^ ((R & 7) << 2))] = a[q];
        }
      }
    WAIT_LGKM0; BARRIER_RAW;

    // A19: elementwise gates; thread -> (eb, en); read swizzle key (eb&7)<<2
    {
      const int sk = (eb & 7) << 2;
      float g0 = bi0, g1 = bi1, g2 = bi2, g3 = bi3;
#pragma unroll
      for (int q = 0; q < 4; ++q) {
        const float* pp = &part[(q * 64 + eb) * 32];
        g0 += pp[en ^ sk]; g1 += pp[(8 + en) ^ sk];
        g2 += pp[(16 + en) ^ sk]; g3 += pp[(24 + en) ^ sk];
      }
      float ig = fast_sig(g0), fg = fast_sig(g1);
      float gg = fast_tanh(g2), og = fast_sig(g3);
      c_reg = fg * c_reg + ig * gg;
      float h = og * fast_tanh(c_reg);
      outD[(size_t)eb * (Ss * Hh) + (size_t)t * Hh + n0 + en] = h;
      // agent-scope packed store of (en, en+1) -> visible at MALL
      float hn = __shfl_xor(h, 1);
      if (!(tid & 1)) {
        union { bf16_t b[2]; uint32_t u32; } pk;
        pk.b[0] = (bf16_t)h; pk.b[1] = (bf16_t)hn;
        uint32_t* dst = (uint32_t*)&hr[(size_t)(step & 1) * (Bb * Hh) +
                                       (size_t)eb * Hh + n0 + en];
        __hip_atomic_store(dst, pk.u32, __ATOMIC_RELAXED, __HIP_MEMORY_SCOPE_AGENT);
      }
    }
    // A20: drain everything (X0' has had ~full H1-phase to land), barrier so
    // ALL waves' h-stores are at MALL, then publish this block's flag.
    WAIT_VM(0); WAIT_LGKM0; BARRIER_RAW;
    if (tid == 0) {
      __hip_atomic_store(&myflags[db], step + 1, __ATOMIC_RELAXED,
                         __HIP_MEMORY_SCOPE_AGENT);
    }
  }
#undef COMPUTE
}

extern "C" void kernel_launch(void* const* d_in, const int* in_sizes, int n_in,
                              void* d_out, int out_size, void* d_ws, size_t ws_size,
                              hipStream_t stream) {
  (void)in_sizes; (void)n_in; (void)out_size;
  const float* xf    = (const float*)d_in[0];
  const float* xb    = (const float*)d_in[1];
  const float* Wih_f = (const float*)d_in[2];
  const float* Whh_f = (const float*)d_in[3];
  const float* bih_f = (const float*)d_in[4];
  const float* bhh_f = (const float*)d_in[5];
  const float* Wih_b = (const float*)d_in[6];
  const float* Whh_b = (const float*)d_in[7];
  const float* bih_b = (const float*)d_in[8];
  const float* bhh_b = (const float*)d_in[9];
  float* outp = (float*)d_out;
  char* ws = (char*)d_ws;
  int* flagsp = (int*)(ws + WS_FLAGS);
  bf16_t* hringp = (bf16_t*)(ws + WS_HRING);
  const bf16_t* xbfp = (const bf16_t*)(ws + WS_XBF);
  const bool use_xbf = ws_size >= WS_NEED_XBF;

  hipLaunchKernelGGL(k_init, dim3(1), dim3(256), 0, stream, flagsp);
  if (use_xbf) {
    hipLaunchKernelGGL(k_convx, dim3(32768), dim3(256), 0, stream,
                       xf, xb, (bf16_t*)(ws + WS_XBF));
  }

  void* args[] = {&xf, &xb, &Wih_f, &Whh_f, &bih_f, &bhh_f,
                  &Wih_b, &Whh_b, &bih_b, &bhh_b,
                  &outp, &xbfp, &hringp, &flagsp};
  if (use_xbf) {
    void (*kp)(const float*, const float*, const float*, const float*,
               const float*, const float*, const float*, const float*,
               const float*, const float*, float*, const bf16_t*, bf16_t*, int*) =
        k_lstm<true>;
    hipFuncSetAttribute((const void*)kp, hipFuncAttributeMaxDynamicSharedMemorySize,
                        LDS_TOTAL);
    hipLaunchCooperativeKernel((const void*)kp, dim3(256), dim3(512), args,
                               LDS_TOTAL, stream);
  } else {
    void (*kp)(const float*, const float*, const float*, const float*,
               const float*, const float*, const float*, const float*,
               const float*, const float*, float*, const bf16_t*, bf16_t*, int*) =
        k_lstm<false>;
    hipFuncSetAttribute((const void*)kp, hipFuncAttributeMaxDynamicSharedMemorySize,
                        LDS_TOTAL);
    hipLaunchCooperativeKernel((const void*)kp, dim3(256), dim3(512), args,
                               LDS_TOTAL, stream);
  }
}